// Round 13
// baseline (62.927 us; speedup 1.0000x reference)
//
#include <hip/hip_runtime.h>
#include <hip/hip_bf16.h>

// Problem constants (from reference): B=262144, D=256, S=16, C=10.
#define D_DIM 256
#define S_SYS 16
#define C_CLS 10
#define BLK   1024                 // 16 waves/block, 1 block/CU (LDS-capped)
                                   // NOTE: 1024-thread block => VGPR must stay <=128
#define GRID  256
#define CPB   128                  // samples per chunk (1024 threads / 8 lanes-per-sample)

// LDS W layout (UNCHANGED from R9/R12):
//   u32 = 2 packed f16 (dims d, d+1)
//   slot(s, c, q, v) = s*S_STR + c*C_STR + q*L_STR + v   (v = 0..15 real, 16..19 pad)
//   v = 2j + t  ->  weight u32 for dims  j*32 + q*4 + 2t .. +1
// Per-lane, per-class: 16 CONTIGUOUS u32 -> 4x ds_read_b128; each 8-lane group's
// starts (20q mod 32) cover all 32 banks exactly once -> conflict-free.
//
// R13 change (single variable): pipeline depth 2 -> 3 chunks of lookahead.
// Two f32 in-flight buffers (F0,F1; 32 VGPR each) + ONE packed-f16 compute
// buffer P (16 VGPR): chunk t+2's loads are issued while chunk t computes,
// giving ~1300 cyc load->use distance vs ~900 cyc HBM latency (m126). The
// old 2-deep structure exposed ~250 cyc of stall per step (58us = 1.30x the
// 44.5us stream floor).
#define L_STR 20
#define C_STR 160      // 8 * L_STR
#define S_STR 1604     // C_CLS * C_STR + 4

typedef __attribute__((ext_vector_type(2))) __fp16 half2v;

__device__ __forceinline__ half2v pack2(float x, float y) {
    return __builtin_amdgcn_cvt_pkrtz(x, y);     // v_cvt_pkrtz_f16_f32
}

__device__ __forceinline__ float fdot2(unsigned w, half2v xp, float c) {
#if __has_builtin(__builtin_amdgcn_fdot2)
    return __builtin_amdgcn_fdot2(__builtin_bit_cast(half2v, w), xp, c, false);
#else
    float d;
    unsigned xu = __builtin_bit_cast(unsigned, xp);
    asm("v_dot2_f32_f16 %0, %1, %2, %3" : "=v"(d) : "v"(w), "v"(xu), "v"(c));
    return d;
#endif
}

__device__ __forceinline__ void load_x(float4 xb[8], const float* __restrict__ x,
                                       long i, int n, int q) {
    const long r = (i < n) ? i : (long)(n - 1);           // clamp (store is masked)
    const float4* p = (const float4*)(x + r * D_DIM) + q; // dims j*32 + q*4 .. +3
    #pragma unroll
    for (int j = 0; j < 8; ++j) xb[j] = p[j * 8];
}

__device__ __forceinline__ int load_sid(const int* __restrict__ sid, long i, int n) {
    return sid[(i < n) ? i : (long)(n - 1)] & (S_SYS - 1);
}

// f32 buffer -> packed f16 pairs (waits on the buffer's loads via data dep;
// frees the f32 registers for the next prefetch)
__device__ __forceinline__ void pack_x(half2v xp[16], const float4 xb[8]) {
    #pragma unroll
    for (int j = 0; j < 8; ++j) {
        xp[2 * j]     = pack2(xb[j].x, xb[j].y);
        xp[2 * j + 1] = pack2(xb[j].z, xb[j].w);
    }
}

__device__ __forceinline__ void step_compute(const half2v xp[16], long i, int n, int q, int s,
                                             const unsigned* __restrict__ Wl,
                                             const float* __restrict__ bl,
                                             float* __restrict__ out) {
    const unsigned* wp = Wl + (unsigned)s * S_STR + (unsigned)q * L_STR;

    float acc[C_CLS];
    #pragma unroll
    for (int c = 0; c < C_CLS; ++c) {
        float a = 0.f;
        #pragma unroll
        for (int k = 0; k < 4; ++k) {                     // uint4 = slots v=4k..4k+3
            const uint4 wv = *(const uint4*)&wp[c * C_STR + 4 * k];
            a = fdot2(wv.x, xp[4 * k + 0], a);
            a = fdot2(wv.y, xp[4 * k + 1], a);
            a = fdot2(wv.z, xp[4 * k + 2], a);
            a = fdot2(wv.w, xp[4 * k + 3], a);
        }
        acc[c] = a;
    }

    // all-reduce each class within the 8-lane group (xor 1,2,4 stay in-group)
    float v0 = 0.f, v1 = 0.f;
    #pragma unroll
    for (int c = 0; c < C_CLS; ++c) {
        float r = acc[c];
        r += __shfl_xor(r, 1);
        r += __shfl_xor(r, 2);
        r += __shfl_xor(r, 4);
        if (c == q)     v0 = r;   // compile-time c, runtime compare (no scratch)
        if (c == 8 + q) v1 = r;
    }
    if (i < n) {
        float* op = out + i * C_CLS;
        op[q] = v0 + bl[s * C_CLS + q];
        if (q < 2) op[8 + q] = v1 + bl[s * C_CLS + 8 + q];
    }
}

__global__ __launch_bounds__(BLK) void mainf_k(const float* __restrict__ x,
                                               const int* __restrict__ sid,
                                               const float* __restrict__ W,
                                               const float* __restrict__ b,
                                               float* __restrict__ out, int n) {
    __shared__ unsigned Wl[S_SYS * S_STR];    // 102,656 B
    __shared__ float    bl[S_SYS * C_CLS];    // 640 B

    const int tid = threadIdx.x;
    const int nch = (n + CPB - 1) / CPB;
    const int cpb = (nch + (int)gridDim.x - 1) / (int)gridDim.x;  // chunks per block
    const int c0 = (int)blockIdx.x * cpb;
    const int c1 = (c0 + cpb < nch) ? (c0 + cpb) : nch;
    if (c0 >= c1) return;                     // whole block exits (before any sync)

    // ---- stage all 16 systems' W (f32 -> packed f16 pairs, RTZ), permuted ----
    const float2* __restrict__ Wg = (const float2*)W;   // pair-index: sc*128 + j*16 + q*2 + t
    for (int u = tid; u < S_SYS * C_CLS * 8 * 16; u += BLK) {   // 20480 real slots
        const int v  = u & 15;
        const int q  = (u >> 4) & 7;
        const int sc = u >> 7;                 // s*10 + c
        const int j  = v >> 1, t = v & 1;
        const float2 f = Wg[(size_t)sc * 128 + j * 16 + q * 2 + t];
        const int s = sc / C_CLS, c = sc - s * C_CLS;
        Wl[s * S_STR + c * C_STR + q * L_STR + v] =
            __builtin_bit_cast(unsigned, pack2(f.x, f.y));
    }
    if (tid < S_SYS * C_CLS) bl[tid] = b[tid];
    __syncthreads();

    const int g = tid >> 3;                   // group (0..127) = sample within chunk
    const int q = tid & 7;                    // lane within group

    // ---- 3-deep pipeline: F0/F1 in flight, P packed-current ----
    float4 F0[8], F1[8];
    half2v P[16];
    int s0 = 0, s1 = 0;

    {
        const long i0 = (long)c0 * CPB + g;
        load_x(F0, x, i0, n, q);
        s0 = load_sid(sid, i0, n);
    }
    if (c0 + 1 < c1) {
        const long i1 = (long)(c0 + 1) * CPB + g;
        load_x(F1, x, i1, n, q);
        s1 = load_sid(sid, i1, n);
    }

    int cur = c0;
    while (true) {
        // ---- consume F0 (chunk cur) ----
        {
            pack_x(P, F0);                               // waits F0's loads
            const long iu = (long)cur * CPB + g;
            const int su = s0;
            const int cn = cur + 2;
            if (cn < c1) {                               // refill F0 2 ahead
                const long in2 = (long)cn * CPB + g;
                load_x(F0, x, in2, n, q);
                s0 = load_sid(sid, in2, n);
            }
            step_compute(P, iu, n, q, su, Wl, bl, out);
        }
        if (++cur >= c1) break;

        // ---- consume F1 (chunk cur) ----
        {
            pack_x(P, F1);                               // waits F1's loads
            const long iu = (long)cur * CPB + g;
            const int su = s1;
            const int cn = cur + 2;
            if (cn < c1) {                               // refill F1 2 ahead
                const long in2 = (long)cn * CPB + g;
                load_x(F1, x, in2, n, q);
                s1 = load_sid(sid, in2, n);
            }
            step_compute(P, iu, n, q, su, Wl, bl, out);
        }
        if (++cur >= c1) break;
    }
}

extern "C" void kernel_launch(void* const* d_in, const int* in_sizes, int n_in,
                              void* d_out, int out_size, void* d_ws, size_t ws_size,
                              hipStream_t stream) {
    const float* x = (const float*)d_in[0];
    const int* sid = (const int*)d_in[1];
    const float* W = (const float*)d_in[2];
    const float* b = (const float*)d_in[3];
    float* out = (float*)d_out;
    const int n = in_sizes[1];   // B

    mainf_k<<<GRID, BLK, 0, stream>>>(x, sid, W, b, out, n);
}

// Round 14
// 62.377 us; speedup vs baseline: 1.0088x; 1.0088x over previous
//
#include <hip/hip_runtime.h>
#include <hip/hip_bf16.h>

// Problem constants (from reference): B=262144, D=256, S=16, C=10.
#define D_DIM 256
#define S_SYS 16
#define C_CLS 10
#define BLK   1024                 // 16 waves/block, 1 block/CU (LDS-capped)
                                   // NOTE: 1024-thread block => VGPR must stay <=128
#define GRID  256
#define CPB   128                  // samples per chunk (1024 threads / 8 lanes-per-sample)

// LDS W layout (UNCHANGED from R9/R12):
//   u32 = 2 packed f16 (dims d, d+1)
//   slot(s, c, q, v) = s*S_STR + c*C_STR + q*L_STR + v   (v = 0..15 real, 16..19 pad)
//   v = 2j + t  ->  weight u32 for dims  j*32 + q*4 + 2t .. +1
// Per-lane, per-class: 16 CONTIGUOUS u32 -> 4x ds_read_b128; each 8-lane group's
// starts (20q mod 32) cover all 32 banks exactly once -> conflict-free.
//
// R13 post-mortem: 3-deep pipeline regressed (single P buffer = WAR serialization)
// -> reverted to R12's 2-deep. R14 change: startup serialization removal.
//  (1) prep_k pre-packs W into the permuted f16 image in d_ws (103 KB) once per
//      call; main staging becomes a LINEAR uint4 copy (7 coalesced iters, no
//      div/cvt, half the bytes of the f32 path).
//  (2) F0/F1 x+sid loads issue BEFORE the staging copy -> the 268 MB x stream
//      primes during staging + barrier instead of after it.
#define L_STR 20
#define C_STR 160      // 8 * L_STR
#define S_STR 1604     // C_CLS * C_STR + 4
#define WIMG_U32 (S_SYS * S_STR)   // 25,664 u32 = 102,656 B (div by 4 -> uint4 copy)

typedef __attribute__((ext_vector_type(2))) __fp16 half2v;

__device__ __forceinline__ half2v pack2(float x, float y) {
    return __builtin_amdgcn_cvt_pkrtz(x, y);     // v_cvt_pkrtz_f16_f32
}

__device__ __forceinline__ float fdot2(unsigned w, half2v xp, float c) {
#if __has_builtin(__builtin_amdgcn_fdot2)
    return __builtin_amdgcn_fdot2(__builtin_bit_cast(half2v, w), xp, c, false);
#else
    float d;
    unsigned xu = __builtin_bit_cast(unsigned, xp);
    asm("v_dot2_f32_f16 %0, %1, %2, %3" : "=v"(d) : "v"(w), "v"(xu), "v"(c));
    return d;
#endif
}

// ---- prep: W (f32) -> permuted packed-f16 image in d_ws ----
__global__ __launch_bounds__(256) void prep_k(const float* __restrict__ W,
                                              unsigned* __restrict__ wimg) {
    const int u = blockIdx.x * 256 + threadIdx.x;       // 0 .. 20479 real slots
    if (u >= S_SYS * C_CLS * 8 * 16) return;
    const int v  = u & 15;
    const int q  = (u >> 4) & 7;
    const int sc = u >> 7;                              // s*10 + c
    const int j  = v >> 1, t = v & 1;
    const float2 f = ((const float2*)W)[(size_t)sc * 128 + j * 16 + q * 2 + t];
    const int s = sc / C_CLS, c = sc - s * C_CLS;
    wimg[s * S_STR + c * C_STR + q * L_STR + v] =
        __builtin_bit_cast(unsigned, pack2(f.x, f.y));
}

__device__ __forceinline__ void load_x(float4 xb[8], const float* __restrict__ x,
                                       long i, int n, int q) {
    const long r = (i < n) ? i : (long)(n - 1);           // clamp (store is masked)
    const float4* p = (const float4*)(x + r * D_DIM) + q; // dims j*32 + q*4 .. +3
    #pragma unroll
    for (int j = 0; j < 8; ++j) xb[j] = p[j * 8];
}

__device__ __forceinline__ int load_sid(const int* __restrict__ sid, long i, int n) {
    return sid[(i < n) ? i : (long)(n - 1)] & (S_SYS - 1);
}

__device__ __forceinline__ void pack_x(half2v xp[16], const float4 xb[8]) {
    #pragma unroll
    for (int j = 0; j < 8; ++j) {
        xp[2 * j]     = pack2(xb[j].x, xb[j].y);
        xp[2 * j + 1] = pack2(xb[j].z, xb[j].w);
    }
}

__device__ __forceinline__ void step_compute(const half2v xp[16], long i, int n, int q, int s,
                                             const unsigned* __restrict__ Wl,
                                             const float* __restrict__ bl,
                                             float* __restrict__ out) {
    const unsigned* wp = Wl + (unsigned)s * S_STR + (unsigned)q * L_STR;

    float acc[C_CLS];
    #pragma unroll
    for (int c = 0; c < C_CLS; ++c) {
        float a = 0.f;
        #pragma unroll
        for (int k = 0; k < 4; ++k) {                     // uint4 = slots v=4k..4k+3
            const uint4 wv = *(const uint4*)&wp[c * C_STR + 4 * k];
            a = fdot2(wv.x, xp[4 * k + 0], a);
            a = fdot2(wv.y, xp[4 * k + 1], a);
            a = fdot2(wv.z, xp[4 * k + 2], a);
            a = fdot2(wv.w, xp[4 * k + 3], a);
        }
        acc[c] = a;
    }

    float v0 = 0.f, v1 = 0.f;
    #pragma unroll
    for (int c = 0; c < C_CLS; ++c) {
        float r = acc[c];
        r += __shfl_xor(r, 1);
        r += __shfl_xor(r, 2);
        r += __shfl_xor(r, 4);
        if (c == q)     v0 = r;   // compile-time c, runtime compare (no scratch)
        if (c == 8 + q) v1 = r;
    }
    if (i < n) {
        float* op = out + i * C_CLS;
        op[q] = v0 + bl[s * C_CLS + q];
        if (q < 2) op[8 + q] = v1 + bl[s * C_CLS + 8 + q];
    }
}

__global__ __launch_bounds__(BLK) void mainf_k(const float* __restrict__ x,
                                               const int* __restrict__ sid,
                                               const unsigned* __restrict__ wimg,
                                               const float* __restrict__ W,   // fallback path
                                               const float* __restrict__ b,
                                               float* __restrict__ out, int n, int use_ws) {
    __shared__ uint4 Wl4[WIMG_U32 / 4];       // 102,656 B, 16B-aligned
    __shared__ float bl[S_SYS * C_CLS];       // 640 B
    unsigned* Wl = (unsigned*)Wl4;

    const int tid = threadIdx.x;
    const int nch = (n + CPB - 1) / CPB;
    const int cpb = (nch + (int)gridDim.x - 1) / (int)gridDim.x;  // chunks per block
    const int c0 = (int)blockIdx.x * cpb;
    const int c1 = (c0 + cpb < nch) ? (c0 + cpb) : nch;
    if (c0 >= c1) return;                     // whole block exits (before any sync)

    const int g = tid >> 3;                   // group (0..127) = sample within chunk
    const int q = tid & 7;                    // lane within group

    // ---- (2) issue F0/F1 x+sid loads FIRST: x stream primes during staging ----
    float4 F0[8], F1[8];
    int s0 = 0, s1 = 0;
    const long i0 = (long)c0 * CPB + g;
    load_x(F0, x, i0, n, q);
    s0 = load_sid(sid, i0, n);
    const bool has1 = (c0 + 1 < c1);
    if (has1) {
        const long i1 = (long)(c0 + 1) * CPB + g;
        load_x(F1, x, i1, n, q);
        s1 = load_sid(sid, i1, n);
    }

    // ---- (1) stage W: linear coalesced copy of the pre-packed image ----
    if (use_ws) {
        const uint4* __restrict__ src = (const uint4*)wimg;
        #pragma unroll
        for (int t = 0; t < 7; ++t) {
            const int u = tid + t * BLK;
            if (u < WIMG_U32 / 4) Wl4[u] = src[u];
        }
    } else {
        // fallback: in-kernel pack (R12 path), used only if ws too small
        const float2* __restrict__ Wg = (const float2*)W;
        for (int u = tid; u < S_SYS * C_CLS * 8 * 16; u += BLK) {
            const int v  = u & 15;
            const int qq = (u >> 4) & 7;
            const int sc = u >> 7;
            const int j  = v >> 1, t = v & 1;
            const float2 f = Wg[(size_t)sc * 128 + j * 16 + qq * 2 + t];
            const int s = sc / C_CLS, c = sc - s * C_CLS;
            Wl[s * S_STR + c * C_STR + qq * L_STR + v] =
                __builtin_bit_cast(unsigned, pack2(f.x, f.y));
        }
    }
    if (tid < S_SYS * C_CLS) bl[tid] = b[tid];
    __syncthreads();

    // ---- 2-deep pipeline (R12 structure, unchanged) ----
    half2v P[16];
    int cur = c0;
    while (true) {
        {
            pack_x(P, F0);                               // waits F0's loads
            const long iu = (long)cur * CPB + g;
            const int su = s0;
            const int cn = cur + 2;
            if (cn < c1) {
                const long in2 = (long)cn * CPB + g;
                load_x(F0, x, in2, n, q);
                s0 = load_sid(sid, in2, n);
            }
            step_compute(P, iu, n, q, su, Wl, bl, out);
        }
        if (++cur >= c1) break;

        {
            pack_x(P, F1);                               // waits F1's loads
            const long iu = (long)cur * CPB + g;
            const int su = s1;
            const int cn = cur + 2;
            if (cn < c1) {
                const long in2 = (long)cn * CPB + g;
                load_x(F1, x, in2, n, q);
                s1 = load_sid(sid, in2, n);
            }
            step_compute(P, iu, n, q, su, Wl, bl, out);
        }
        if (++cur >= c1) break;
    }
}

extern "C" void kernel_launch(void* const* d_in, const int* in_sizes, int n_in,
                              void* d_out, int out_size, void* d_ws, size_t ws_size,
                              hipStream_t stream) {
    const float* x = (const float*)d_in[0];
    const int* sid = (const int*)d_in[1];
    const float* W = (const float*)d_in[2];
    const float* b = (const float*)d_in[3];
    float* out = (float*)d_out;
    const int n = in_sizes[1];   // B

    const int use_ws = (ws_size >= (size_t)WIMG_U32 * 4) ? 1 : 0;
    unsigned* wimg = (unsigned*)d_ws;

    if (use_ws) {
        const int nslots = S_SYS * C_CLS * 8 * 16;       // 20480
        prep_k<<<(nslots + 255) / 256, 256, 0, stream>>>(W, wimg);
    }
    mainf_k<<<GRID, BLK, 0, stream>>>(x, sid, wimg, W, b, out, n, use_ws);
}